// Round 1
// baseline (77.778 us; speedup 1.0000x reference)
//
#include <hip/hip_runtime.h>
#include <math.h>

#define HH 512
#define WW 512
#define M 2048          // 64 segs * 32 samples = path points / edges
#define TPB 256
#define TWIN 18         // sigmoid truncation half-width (error <= e^-18 per edge)
#define WPIX 37         // 2*TWIN+1 pixels per window
#define EPB 6           // 6 edges per dense pass (6*37 = 222 active lanes)
#define CAP 2048        // per-row record capacity (hard upper bound = #edges)

// ws layout:
//   cnt : 512 int     @ ws + 0      (2 KB, zeroed each launch)
//   rec : 512*CAP f2  @ ws + 4096   (8 MB)

// fast sigmoid: v_exp + v_rcp (1-ulp rcp; error budget has ~5x margin)
__device__ __forceinline__ float sigmoidf(float z) {
    return __builtin_amdgcn_rcpf(1.0f + __expf(-z));
}

// identical arithmetic to the old phase-1 sampler (bit-exact acceptance set)
__device__ __forceinline__ float2 sample_pt(const float2* __restrict__ cp2, int m) {
    int s = m >> 5;
    int i = m & 31;
    float tt = (float)i * (1.0f / 31.0f);
    float mt = 1.0f - tt;
    float w0 = mt * mt * mt;
    float w1 = 3.0f * mt * mt * tt;
    float w2 = 3.0f * mt * tt * tt;
    float w3 = tt * tt * tt;
    float2 P0 = cp2[3 * s], P1 = cp2[3 * s + 1];
    float2 P2 = cp2[3 * s + 2], P3 = cp2[3 * s + 3];
    return make_float2(w0 * P0.x + w1 * P1.x + w2 * P2.x + w3 * P3.x,
                       w0 * P0.y + w1 * P1.y + w2 * P2.y + w3 * P3.y);
}

// ---- K0: zero the per-row record counters (poisoned workspace) ----
__global__ __launch_bounds__(256) void zero_kernel(int* __restrict__ cnt) {
    int t = threadIdx.x;
    cnt[t] = 0;
    cnt[t + 256] = 0;
}

// ---- K1: one WAVE per edge; lanes cover the edge's active rows ----
// Emits (x_cross, w) records into per-row lists. Acceptance predicate and
// all float math are identical to the old per-row scan, so the record set
// is bit-identical; only atomic append order differs.
__global__ __launch_bounds__(TPB) void bin_kernel(
    const float* __restrict__ cp,
    int* __restrict__ cnt,
    float2* __restrict__ rec)
{
    const int lane = threadIdx.x & 63;
    const int e = (blockIdx.x << 2) + (threadIdx.x >> 6);  // 4 edges / block

    const float2* cp2 = (const float2*)cp;
    float2 a = sample_pt(cp2, e);
    float2 b = sample_pt(cp2, (e + 1) & (M - 1));

    float dy = b.y - a.y;
    if (!(fabsf(dy) >= 1e-6f)) return;        // wave-uniform reject (joins/horizontals)

    float d    = dy + 1e-8f;
    float rcpd = __builtin_amdgcn_rcpf(d);

    // active rows: tc in (-0.8059, 1.8059)  =>  gy in [a.y-0.8059d, a.y+1.8059d]
    // (order depends on sign of d). Widen 1 row each side; the exact per-row
    // predicate below re-filters, so widening is purely conservative.
    float g0 = fmaf(-0.8059f, d, a.y);
    float g1 = fmaf( 1.8059f, d, a.y);
    float lo = fminf(g0, g1), hi = fmaxf(g0, g1);
    int r0 = (int)floorf(lo); if (r0 < 0)  r0 = 0;
    int r1 = (int)ceilf(hi);  if (r1 > HH - 1) r1 = HH - 1;

    float dx = b.x - a.x;
    for (int r = r0 + lane; r <= r1; r += 64) {
        float gy = (float)r;
        float tc = (gy - a.y) * rcpd;
        if (!(tc > -0.8059f) || !(tc < 1.8059f)) continue;   // same compares as before
        float ea = __expf(-20.0f * tc);
        float eb = __expf(-20.0f * (1.0f - tc));
        float v  = __builtin_amdgcn_rcpf((1.0f + ea) * (1.0f + eb));
        float w  = (dy > 0.0f) ? v : -v;                     // valid_t * sign(dy)
        float xc = fmaf(tc, dx, a.x);
        int A = (int)floorf(xc) - TWIN;
        if (A > -WPIX) {                                     // step and/or window part
            int idx = atomicAdd(&cnt[r], 1);
            if (idx < CAP) rec[(r << 11) + idx] = make_float2(xc, w);
        }
    }
}

// ---- K2: per-row render from the record list (old phases 2b..4 only) ----
__global__ __launch_bounds__(TPB) void render_kernel(
    const int*    __restrict__ cnt,
    const float2* __restrict__ rec,
    const float*  __restrict__ color,
    float* __restrict__ out)
{
    __shared__ float2 act[CAP];        // 16 KB staged records
    __shared__ float  smoothv[WW];     // windowed (exact) sigmoid part
    __shared__ float  cbin[WW + 1];    // step-part bins
    __shared__ float  wtot[4];         // per-wave scan totals

    const int t    = threadIdx.x;
    const int lane = t & 63;
    const int wv   = t >> 6;
    const int y    = blockIdx.x;

    int na = cnt[y];
    if (na > CAP) na = CAP;

    for (int x = t; x < WW; x += TPB) { smoothv[x] = 0.0f; cbin[x] = 0.0f; }
    if (t == 0) cbin[WW] = 0.0f;
    __syncthreads();

    // stage records + step-part bin adds (identical bin rule as before)
    for (int e2 = t; e2 < na; e2 += TPB) {
        float2 xw = rec[(y << 11) + e2];
        act[e2] = xw;
        int A = (int)floorf(xw.x) - TWIN;
        int bin = (A > WW) ? WW : A;
        if (bin > 0) atomicAdd(&cbin[bin], xw.y);
    }
    __syncthreads();

    // dense windowed pass: 37 lanes per active edge, 6 edges/pass
    {
        int el = t / WPIX;               // 0..6 (lanes 222..255 idle)
        int k  = t - el * WPIX;          // 0..36
        if (el < EPB) {
            for (int e2 = el; e2 < na; e2 += EPB) {
                float2 xw = act[e2];
                int x = (int)floorf(xw.x) - TWIN + k;
                if ((unsigned)x < (unsigned)WW) {
                    atomicAdd(&smoothv[x], xw.y * sigmoidf(xw.x - (float)x));
                }
            }
        }
    }
    __syncthreads();

    // suffix scan of cbin: wind_const[x] = sum_{j>x} cbin[j]
    float e0 = cbin[2 * t];
    float e1 = cbin[2 * t + 1];
    float p  = e0 + e1;
    float v  = p;
#pragma unroll
    for (int off = 1; off < 64; off <<= 1) {
        float o = __shfl_down(v, off, 64);
        if (lane + off < 64) v += o;
    }
    if (lane == 0) wtot[wv] = v;
    __syncthreads();
    float hsum = 0.0f;
    if (wv < 1) hsum += wtot[1];
    if (wv < 2) hsum += wtot[2];
    if (wv < 3) hsum += wtot[3];
    float S    = v - p + hsum;
    float c512 = cbin[WW];
    float wc1  = S + c512;
    float wc0  = e1 + wc1;

    // alpha + output
    float r = color[0], g = color[1], bl = color[2];
    int x0 = 2 * t;
    float a0 = sigmoidf(4.0f * (wc0 + smoothv[x0]));
    float a1 = sigmoidf(4.0f * (wc1 + smoothv[x0 + 1]));
    float4* out4 = (float4*)out;
    out4[y * WW + x0]     = make_float4(r, g, bl, a0);
    out4[y * WW + x0 + 1] = make_float4(r, g, bl, a1);
}

extern "C" void kernel_launch(void* const* d_in, const int* in_sizes, int n_in,
                              void* d_out, int out_size, void* d_ws, size_t ws_size,
                              hipStream_t stream) {
    const float* cp    = (const float*)d_in[0];   // (193,2) float32
    const float* color = (const float*)d_in[1];   // (3,) float32
    float* out = (float*)d_out;                   // (512,512,4) float32

    int*    cnt = (int*)d_ws;
    float2* rec = (float2*)((char*)d_ws + 4096);

    zero_kernel  <<<dim3(1),     dim3(256), 0, stream>>>(cnt);
    bin_kernel   <<<dim3(M / 4), dim3(TPB), 0, stream>>>(cp, cnt, rec);
    render_kernel<<<dim3(HH),    dim3(TPB), 0, stream>>>(cnt, rec, color, out);
}

// Round 2
// 77.675 us; speedup vs baseline: 1.0013x; 1.0013x over previous
//
#include <hip/hip_runtime.h>
#include <math.h>

#define HH 512
#define WW 512
#define M 2048          // 64 segs * 32 samples = path points / edges
#define TPB 512         // 8 waves: waves 0-3 -> row y0, waves 4-7 -> row y0+1
#define ROWS 2          // rows per block (amortizes sampling + edge scan)
#define TWIN 18         // sigmoid truncation half-width (error <= e^-18 per edge)
#define WPIX 37         // 2*TWIN+1 pixels per window
#define EPB 6           // 6 edges per dense pass (6*37 = 222 active lanes of 256)

// fast sigmoid: v_exp + v_rcp (1-ulp rcp; error budget has ~5x margin)
__device__ __forceinline__ float sigmoidf(float z) {
    return __builtin_amdgcn_rcpf(1.0f + __expf(-z));
}

__global__ __launch_bounds__(TPB) void bezier_render_kernel(
    const float* __restrict__ cp,     // 193*2 floats
    const float* __restrict__ color,  // 3 floats
    float* __restrict__ out)          // H*W*4 floats, channel-last
{
    __shared__ float2 cps2[194];            // control points as float2
    __shared__ float2 pts[M];               // 16 KB sampled path (shared by both rows)
    __shared__ float  smoothv[ROWS][WW];    // windowed (exact) sigmoid part, per row
    __shared__ float  cbin[ROWS][WW + 1];   // step-part bins, per row
    __shared__ float  wtot[ROWS][4];        // per-wave scan totals, per row
    __shared__ float2 act[ROWS][M];         // compacted (x_cross, w), per row (32 KB)
    __shared__ int    nact[ROWS];

    const int t    = threadIdx.x;
    const int lane = t & 63;
    const int grp  = t >> 8;          // 0/1: which row this thread's wave serves
    const int tl   = t & 255;         // thread id within row group
    const int wv   = tl >> 6;         // wave within row group (0..3)
    const int y0   = blockIdx.x * ROWS;

    // ---- 0) stage control points; init accumulators ----
    if (t < 193) cps2[t] = ((const float2*)cp)[t];
    if (t < ROWS) { nact[t] = 0; cbin[t][WW] = 0.0f; }
    for (int x = t; x < ROWS * WW; x += TPB) smoothv[x >> 9][x & (WW - 1)] = 0.0f;
    for (int x = t; x < ROWS * WW; x += TPB) cbin[x >> 9][x & (WW - 1)] = 0.0f;
    __syncthreads();

    // ---- 1) sample cubic beziers into LDS (once per block = once per 2 rows) ----
    for (int m = t; m < M; m += TPB) {
        int s = m >> 5;          // segment (broadcast across 32 consecutive lanes)
        int i = m & 31;
        float tt = (float)i * (1.0f / 31.0f);
        float mt = 1.0f - tt;
        float w0 = mt * mt * mt;
        float w1 = 3.0f * mt * mt * tt;
        float w2 = 3.0f * mt * tt * tt;
        float w3 = tt * tt * tt;
        float2 P0 = cps2[3 * s], P1 = cps2[3 * s + 1];
        float2 P2 = cps2[3 * s + 2], P3 = cps2[3 * s + 3];
        pts[m] = make_float2(w0 * P0.x + w1 * P1.x + w2 * P2.x + w3 * P3.x,
                             w0 * P0.y + w1 * P1.y + w2 * P2.y + w3 * P3.y);
    }
    __syncthreads();

    // ---- 2a) edge scan: fixed cost paid ONCE for both rows ----
    // valid_t < 1e-7 is implied by tc outside (-0.8059, 1.8059):
    // sigmoid(20*(-0.8059)) = 9.96e-8. dy>=1e-6 checked first so tc is finite.
    for (int e = t; e < M; e += TPB) {       // 4 iterations
        float2 a = pts[e];
        float2 b = pts[(e + 1) & (M - 1)];
        float dy = b.y - a.y;
        if (!(fabsf(dy) >= 1e-6f)) continue;
        float rcpd = __builtin_amdgcn_rcpf(dy + 1e-8f);
        float dx = b.x - a.x;
#pragma unroll
        for (int rr = 0; rr < ROWS; ++rr) {
            float gy = (float)(y0 + rr);
            float tc = (gy - a.y) * rcpd;
            if (!(tc > -0.8059f) || !(tc < 1.8059f)) continue;
            float ea = __expf(-20.0f * tc);
            float eb = __expf(-20.0f * (1.0f - tc));
            float v = __builtin_amdgcn_rcpf((1.0f + ea) * (1.0f + eb));
            float w = (dy > 0.0f) ? v : -v;                 // valid_t * sign(dy)
            float xc = fmaf(tc, dx, a.x);
            int A = (int)floorf(xc) - TWIN;                 // first windowed pixel
            int bin = (A > WW) ? WW : A;                    // pixels x<A get full w
            if (bin > 0) atomicAdd(&cbin[rr][bin], w);
            if (A < WW && A > -WPIX) {                      // window overlaps the row
                int idx = atomicAdd(&nact[rr], 1);
                act[rr][idx] = make_float2(xc, w);
            }
        }
    }
    __syncthreads();

    // ---- 2b) dense windowed pass: per row group, 37 lanes/edge, 6 edges/pass ----
    {
        int na = nact[grp];
        int el = tl / WPIX;              // 0..6 (lanes 222..255 of group idle)
        int k  = tl - el * WPIX;         // 0..36
        if (el < EPB) {
            for (int e = el; e < na; e += EPB) {
                float2 xw = act[grp][e];
                int x = (int)floorf(xw.x) - TWIN + k;
                if ((unsigned)x < (unsigned)WW) {
                    atomicAdd(&smoothv[grp][x], xw.y * sigmoidf(xw.x - (float)x));
                }
            }
        }
    }
    __syncthreads();

    // ---- 3) suffix scan of cbin (per row group): wind_const[x] = sum_{j>x} ----
    float e0 = cbin[grp][2 * tl];
    float e1 = cbin[grp][2 * tl + 1];
    float p  = e0 + e1;
    float v  = p;
#pragma unroll
    for (int off = 1; off < 64; off <<= 1) {
        float o = __shfl_down(v, off, 64);
        if (lane + off < 64) v += o;
    }
    if (lane == 0) wtot[grp][wv] = v;    // wave total = suffix at its first lane
    __syncthreads();
    float hsum = 0.0f;
    if (wv < 1) hsum += wtot[grp][1];
    if (wv < 2) hsum += wtot[grp][2];
    if (wv < 3) hsum += wtot[grp][3];
    float S    = v - p + hsum;           // sum of p(u) for group threads u > tl
    float c512 = cbin[grp][WW];
    float wc1  = S + c512;               // wind_const at x=2tl+1
    float wc0  = e1 + wc1;               // wind_const at x=2tl

    // ---- 4) alpha + output ----
    float r = color[0], g = color[1], bl = color[2];
    int x0 = 2 * tl;
    int y  = y0 + grp;
    float a0 = sigmoidf(4.0f * (wc0 + smoothv[grp][x0]));
    float a1 = sigmoidf(4.0f * (wc1 + smoothv[grp][x0 + 1]));
    float4* out4 = (float4*)out;
    out4[y * WW + x0]     = make_float4(r, g, bl, a0);
    out4[y * WW + x0 + 1] = make_float4(r, g, bl, a1);
}

extern "C" void kernel_launch(void* const* d_in, const int* in_sizes, int n_in,
                              void* d_out, int out_size, void* d_ws, size_t ws_size,
                              hipStream_t stream) {
    const float* cp    = (const float*)d_in[0];  // (193,2) float32
    const float* color = (const float*)d_in[1];  // (3,) float32
    float* out = (float*)d_out;                  // (512,512,4) float32
    bezier_render_kernel<<<dim3(HH / ROWS), dim3(TPB), 0, stream>>>(cp, color, out);
}

// Round 3
// 69.039 us; speedup vs baseline: 1.1266x; 1.1251x over previous
//
#include <hip/hip_runtime.h>
#include <math.h>

#define HH 512
#define WW 512
#define M 2048          // 64 segs * 32 samples = path points / edges
#define TPB 256
#define TWL 15          // window left half-width: A = floor(xc) - TWL
#define WPIX 32         // window pixels; truncation error <= e^-16 per edge
#define EPB 8           // 8 edges per dense pass (8*32 = 256 lanes, none idle)

// fast sigmoid: v_exp + v_rcp (1-ulp rcp; error budget has ~5x margin)
__device__ __forceinline__ float sigmoidf(float z) {
    return __builtin_amdgcn_rcpf(1.0f + __expf(-z));
}

__global__ __launch_bounds__(TPB) void bezier_render_kernel(
    const float* __restrict__ cp,     // 193*2 floats
    const float* __restrict__ color,  // 3 floats
    float* __restrict__ out)          // H*W*4 floats, channel-last
{
    __shared__ float2 cps2[194];       // control points as float2
    __shared__ float2 pts[M];          // 16 KB sampled path
    __shared__ float  smoothv[WW];     // windowed (exact) sigmoid part
    __shared__ float  cbin[WW + 1];    // step-part bins
    __shared__ float  wtot[4];         // per-wave scan totals
    __shared__ float2 act[M];          // compacted (x_cross, w)
    __shared__ int    nact;

    const int t    = threadIdx.x;
    const int lane = t & 63;
    const int wv   = t >> 6;
    const int y    = blockIdx.x;
    const float gy = (float)y;

    // ---- 0) stage control points; init accumulators ----
    if (t < 193) cps2[t] = ((const float2*)cp)[t];
    if (t == 0) { nact = 0; cbin[WW] = 0.0f; }
    for (int x = t; x < WW; x += TPB) { smoothv[x] = 0.0f; cbin[x] = 0.0f; }
    __syncthreads();

    // ---- 1) sample cubic beziers into LDS ----
    for (int m = t; m < M; m += TPB) {
        int s = m >> 5;          // segment (broadcast across 32 consecutive lanes)
        int i = m & 31;
        float tt = (float)i * (1.0f / 31.0f);
        float mt = 1.0f - tt;
        float w0 = mt * mt * mt;
        float w1 = 3.0f * mt * mt * tt;
        float w2 = 3.0f * mt * tt * tt;
        float w3 = tt * tt * tt;
        float2 P0 = cps2[3 * s], P1 = cps2[3 * s + 1];
        float2 P2 = cps2[3 * s + 2], P3 = cps2[3 * s + 3];
        pts[m] = make_float2(w0 * P0.x + w1 * P1.x + w2 * P2.x + w3 * P3.x,
                             w0 * P0.y + w1 * P1.y + w2 * P2.y + w3 * P3.y);
    }
    __syncthreads();

    // ---- 2a) edge scan: rcp-free EARLY REJECT before any transcendental ----
    // valid_t < 1e-7 is implied by tc outside (-0.8059, 1.8059):
    // sigmoid(20*(-0.8059)) = 9.96e-8. Test u/d in range via multiplies
    // (u in (min,max)(-0.8059d, 1.8059d)); rcp only for accepted pairs.
    for (int e = t; e < M; e += TPB) {
        float2 a = pts[e];
        float2 b = pts[(e + 1) & (M - 1)];
        float dy = b.y - a.y;
        if (!(fabsf(dy) >= 1e-6f)) continue;
        float d  = dy + 1e-8f;
        float u  = gy - a.y;
        float g0 = -0.8059f * d;
        float g1 =  1.8059f * d;
        float lo = fminf(g0, g1);
        float hi = fmaxf(g0, g1);
        if (!(u > lo) || !(u < hi)) continue;
        float tc = u * __builtin_amdgcn_rcpf(d);
        float ea = __expf(-20.0f * tc);
        float eb = __expf(-20.0f * (1.0f - tc));
        float v = __builtin_amdgcn_rcpf((1.0f + ea) * (1.0f + eb));
        float w = (dy > 0.0f) ? v : -v;                 // valid_t * sign(dy)
        float xc = fmaf(tc, b.x - a.x, a.x);
        int A = (int)floorf(xc) - TWL;                  // first windowed pixel
        int bin = (A > WW) ? WW : A;                    // pixels x<A get full w
        if (bin > 0) atomicAdd(&cbin[bin], w);
        if (A < WW && A > -WPIX) {                      // window overlaps the row
            int idx = atomicAdd(&nact, 1);              // wave-aggregated by compiler
            act[idx] = make_float2(xc, w);
        }
    }
    __syncthreads();

    // ---- 2b) dense windowed pass: 32 lanes per active edge, 8 edges/pass ----
    {
        int na = nact;
        int el = t >> 5;                 // 0..7
        int k  = t & 31;                 // 0..31
        for (int e = el; e < na; e += EPB) {
            float2 xw = act[e];
            int x = (int)floorf(xw.x) - TWL + k;
            if ((unsigned)x < (unsigned)WW) {
                atomicAdd(&smoothv[x], xw.y * sigmoidf(xw.x - (float)x));
            }
        }
    }
    __syncthreads();

    // ---- 3) suffix scan of cbin: wind_const[x] = sum_{j>x} cbin[j] ----
    // shfl-based in-wave inclusive suffix scan (no barriers), then combine
    // 4 wave totals through LDS with a single barrier.
    float e0 = cbin[2 * t];
    float e1 = cbin[2 * t + 1];
    float p  = e0 + e1;
    float v  = p;
#pragma unroll
    for (int off = 1; off < 64; off <<= 1) {
        float o = __shfl_down(v, off, 64);
        if (lane + off < 64) v += o;
    }
    if (lane == 0) wtot[wv] = v;         // wave total = suffix at its first lane
    __syncthreads();
    float hsum = 0.0f;
    if (wv < 1) hsum += wtot[1];
    if (wv < 2) hsum += wtot[2];
    if (wv < 3) hsum += wtot[3];
    float S    = v - p + hsum;           // sum of p(u) for threads u > t
    float c512 = cbin[WW];
    float wc1  = S + c512;               // wind_const at x=2t+1
    float wc0  = e1 + wc1;               // wind_const at x=2t

    // ---- 4) alpha + output ----
    float r = color[0], g = color[1], bl = color[2];
    int x0 = 2 * t;
    float a0 = sigmoidf(4.0f * (wc0 + smoothv[x0]));
    float a1 = sigmoidf(4.0f * (wc1 + smoothv[x0 + 1]));
    float4* out4 = (float4*)out;
    out4[y * WW + x0]     = make_float4(r, g, bl, a0);
    out4[y * WW + x0 + 1] = make_float4(r, g, bl, a1);
}

extern "C" void kernel_launch(void* const* d_in, const int* in_sizes, int n_in,
                              void* d_out, int out_size, void* d_ws, size_t ws_size,
                              hipStream_t stream) {
    const float* cp    = (const float*)d_in[0];  // (193,2) float32
    const float* color = (const float*)d_in[1];  // (3,) float32
    float* out = (float*)d_out;                  // (512,512,4) float32
    bezier_render_kernel<<<dim3(HH), dim3(TPB), 0, stream>>>(cp, color, out);
}